// Round 1
// baseline (387.378 us; speedup 1.0000x reference)
//
#include <hip/hip_runtime.h>
#include <hip/hip_bf16.h>

typedef unsigned short ushort_t;
typedef __attribute__((ext_vector_type(4))) float f32x4;
typedef __attribute__((ext_vector_type(8))) short s16x8;

#define DEV static __device__ __forceinline__

constexpr int Bb = 2, Nn = 2048, Dd = 768, Hh = 12, FFf = 3072;
constexpr int MTOK = Bb * Nn;           // 4096
constexpr int QKVN = 3 * Dd;            // 2304

DEV float bf2f(unsigned short u) {
    union { unsigned int i; float f; } x; x.i = ((unsigned int)u) << 16; return x.f;
}
DEV unsigned short f2bf(float f) {
    union { float f; unsigned int i; } x; x.f = f;
    unsigned int r = x.i + 0x7FFFu + ((x.i >> 16) & 1u);
    return (unsigned short)(r >> 16);
}

// ---------------- transpose + fp32->bf16 convert: in [K][N] -> out [N][K] ----------------
__global__ void k_transpose(const float* __restrict__ in, unsigned short* __restrict__ out,
                            int K, int N) {
    __shared__ float t[32][33];
    int bx = blockIdx.x * 32, by = blockIdx.y * 32;
    int tx = threadIdx.x, ty = threadIdx.y; // (32,8)
#pragma unroll
    for (int i = 0; i < 4; i++)
        t[ty + 8 * i][tx] = in[(size_t)(by + ty + 8 * i) * N + bx + tx];
    __syncthreads();
#pragma unroll
    for (int i = 0; i < 4; i++)
        out[(size_t)(bx + ty + 8 * i) * K + by + tx] = f2bf(t[tx][ty + 8 * i]);
}

// ---------------- pack coords (B,N,3) -> (B*N) float4 ----------------
__global__ void k_coords(const float* __restrict__ c, float4* __restrict__ out, int n) {
    int i = blockIdx.x * 256 + threadIdx.x;
    if (i < n) out[i] = make_float4(c[3 * i], c[3 * i + 1], c[3 * i + 2], 0.f);
}

// ---------------- LayerNorm fp32 -> bf16 ----------------
DEV float wred_sum(float v) {
#pragma unroll
    for (int o = 32; o; o >>= 1) v += __shfl_down(v, o, 64);
    return v;
}

__global__ __launch_bounds__(256) void k_ln(const float* __restrict__ x,
                                            const float* __restrict__ g,
                                            const float* __restrict__ be,
                                            unsigned short* __restrict__ out) {
    int row = blockIdx.x;
    const float* xr = x + (size_t)row * Dd;
    int t = threadIdx.x;
    float v0 = xr[t], v1 = xr[t + 256], v2 = xr[t + 512];
    float s = v0 + v1 + v2;
    float sq = v0 * v0 + v1 * v1 + v2 * v2;
    __shared__ float r1[4], r2[4];
    float ws = wred_sum(s), wq = wred_sum(sq);
    int wid = t >> 6, lane = t & 63;
    if (lane == 0) { r1[wid] = ws; r2[wid] = wq; }
    __syncthreads();
    s = r1[0] + r1[1] + r1[2] + r1[3];
    sq = r2[0] + r2[1] + r2[2] + r2[3];
    float mean = s * (1.f / Dd);
    float var = sq * (1.f / Dd) - mean * mean;
    float rs = rsqrtf(var + 1e-5f);
    unsigned short* orow = out + (size_t)row * Dd;
    orow[t]       = f2bf((v0 - mean) * rs * g[t]       + be[t]);
    orow[t + 256] = f2bf((v1 - mean) * rs * g[t + 256] + be[t + 256]);
    orow[t + 512] = f2bf((v2 - mean) * rs * g[t + 512] + be[t + 512]);
}

// ---------------- GEMM: A[M][K] bf16 @ Bt[N][K] bf16 + bias, epilogues ----------------
// EPI 0: out bf16 = A@B + bias
// EPI 1: out bf16 = gelu(A@B + bias)
// EPI 2: out f32  = A@B + bias + res
template <int EPI>
__global__ __launch_bounds__(256) void k_gemm(const unsigned short* __restrict__ A,
                                              const unsigned short* __restrict__ Bt,
                                              const float* __restrict__ bias,
                                              const float* __restrict__ res,
                                              void* __restrict__ outp,
                                              int M, int N, int K) {
    constexpr int BM = 128, BN = 128, BK = 32;
    __shared__ unsigned short As[BM][BK + 8];
    __shared__ unsigned short Bs[BN][BK + 8];
    int m0 = blockIdx.y * BM, n0 = blockIdx.x * BN;
    int t = threadIdx.x;
    int wid = t >> 6, lane = t & 63;
    int wr = wid >> 1, wc = wid & 1;
    int lg = lane >> 4, lr = lane & 15;
    f32x4 acc[4][4] = {};

    for (int k0 = 0; k0 < K; k0 += BK) {
        __syncthreads();
#pragma unroll
        for (int i = 0; i < 2; i++) {
            int c = t + 256 * i;
            int row = c >> 2, kc = c & 3;
            *(s16x8*)&As[row][kc * 8] =
                *(const s16x8*)(A + (size_t)(m0 + row) * K + k0 + kc * 8);
            *(s16x8*)&Bs[row][kc * 8] =
                *(const s16x8*)(Bt + (size_t)(n0 + row) * K + k0 + kc * 8);
        }
        __syncthreads();
        s16x8 af[4], bfr[4];
#pragma unroll
        for (int i = 0; i < 4; i++) {
            af[i]  = *(const s16x8*)&As[wr * 64 + i * 16 + lr][lg * 8];
            bfr[i] = *(const s16x8*)&Bs[wc * 64 + i * 16 + lr][lg * 8];
        }
#pragma unroll
        for (int mi = 0; mi < 4; mi++)
#pragma unroll
            for (int ni = 0; ni < 4; ni++)
                acc[mi][ni] = __builtin_amdgcn_mfma_f32_16x16x32_bf16(
                    af[mi], bfr[ni], acc[mi][ni], 0, 0, 0);
    }

    int mrow = m0 + wr * 64;
    int ncol = n0 + wc * 64;
#pragma unroll
    for (int mi = 0; mi < 4; mi++) {
#pragma unroll
        for (int ni = 0; ni < 4; ni++) {
            int nn = ncol + ni * 16 + lr;
            float bs = bias[nn];
#pragma unroll
            for (int r = 0; r < 4; r++) {
                int mm = mrow + mi * 16 + lg * 4 + r;
                float v = acc[mi][ni][r] + bs;
                if (EPI == 1) {
                    v = 0.5f * v * (1.f + erff(v * 0.70710678118f));
                    ((unsigned short*)outp)[(size_t)mm * N + nn] = f2bf(v);
                } else if (EPI == 2) {
                    v += res[(size_t)mm * N + nn];
                    ((float*)outp)[(size_t)mm * N + nn] = v;
                } else {
                    ((unsigned short*)outp)[(size_t)mm * N + nn] = f2bf(v);
                }
            }
        }
    }
}

// ---------------- fused masked flash attention ----------------
// qkv bf16 [B][N][3*768] ; one wave handles (b, h, 16 q-rows)
__global__ __launch_bounds__(64) void k_attn(const unsigned short* __restrict__ qkv,
                                             const float4* __restrict__ c4,
                                             unsigned short* __restrict__ out) {
    int qt = blockIdx.x, h = blockIdx.y, b = blockIdx.z;
    int lane = threadIdx.x;
    int lg = lane >> 4, lr = lane & 15;
    __shared__ unsigned short P[16][40];

    const size_t rs = QKVN;
    const unsigned short* Q = qkv + (size_t)b * Nn * rs + h * 64;
    const unsigned short* Kp = Q + Dd;
    const unsigned short* Vp = Q + 2 * Dd;
    int q0 = qt * 16;

    s16x8 qf0 = *(const s16x8*)(Q + (size_t)(q0 + lr) * rs + lg * 8);
    s16x8 qf1 = *(const s16x8*)(Q + (size_t)(q0 + lr) * rs + 32 + lg * 8);
    float4 cq = c4[b * Nn + q0 + lr];

    float m_run = -1e30f, l_run = 0.f;
    f32x4 oacc[4] = {};

    for (int k0 = 0; k0 < Nn; k0 += 32) {
        f32x4 st[2];
#pragma unroll
        for (int s = 0; s < 2; s++) {
            s16x8 kf0 = *(const s16x8*)(Kp + (size_t)(k0 + s * 16 + lr) * rs + lg * 8);
            s16x8 kf1 = *(const s16x8*)(Kp + (size_t)(k0 + s * 16 + lr) * rs + 32 + lg * 8);
            f32x4 z = {};
            z = __builtin_amdgcn_mfma_f32_16x16x32_bf16(kf0, qf0, z, 0, 0, 0);
            st[s] = __builtin_amdgcn_mfma_f32_16x16x32_bf16(kf1, qf1, st[s] = z, 0, 0, 0);
        }
        // mask + scale; find tile max
        float p[2][4];
        float mt = -1e30f;
#pragma unroll
        for (int s = 0; s < 2; s++) {
#pragma unroll
            for (int r = 0; r < 4; r++) {
                int kk = k0 + s * 16 + lg * 4 + r;
                float4 ck = c4[b * Nn + kk];
                float dx = cq.x - ck.x, dy = cq.y - ck.y, dz = cq.z - ck.z;
                float d2 = dx * dx + dy * dy + dz * dz;
                float sv = st[s][r] * 0.125f;
                p[s][r] = (d2 <= 4.0f) ? sv : -1e30f;
                mt = fmaxf(mt, p[s][r]);
            }
        }
        mt = fmaxf(mt, __shfl_xor(mt, 16, 64));
        mt = fmaxf(mt, __shfl_xor(mt, 32, 64));
        float mn = fmaxf(m_run, mt);
        float fac = expf(m_run - mn);
        float lt = 0.f;
#pragma unroll
        for (int s = 0; s < 2; s++)
#pragma unroll
            for (int r = 0; r < 4; r++) {
                p[s][r] = (p[s][r] > -1e29f) ? expf(p[s][r] - mn) : 0.f;
                lt += p[s][r];
            }
        lt += __shfl_xor(lt, 16, 64);
        lt += __shfl_xor(lt, 32, 64);
        l_run = l_run * fac + lt;
        m_run = mn;
        // rescale output accumulators (rows are q = lg*4+r)
        float fr[4];
#pragma unroll
        for (int r = 0; r < 4; r++) fr[r] = __shfl(fac, (lane & 48) + lg * 4 + r, 64);
#pragma unroll
        for (int dt = 0; dt < 4; dt++)
#pragma unroll
            for (int r = 0; r < 4; r++) oacc[dt][r] *= fr[r];
        // P -> LDS (bf16), re-fragment for PV
#pragma unroll
        for (int s = 0; s < 2; s++)
#pragma unroll
            for (int r = 0; r < 4; r++)
                P[lr][s * 16 + lg * 4 + r] = f2bf(p[s][r]);
        __syncthreads();
        s16x8 pf = *(const s16x8*)&P[lr][lg * 8];
        __syncthreads();
#pragma unroll
        for (int dt = 0; dt < 4; dt++) {
            s16x8 vf;
#pragma unroll
            for (int j = 0; j < 8; j++)
                vf[j] = (short)Vp[(size_t)(k0 + lg * 8 + j) * rs + dt * 16 + lr];
            oacc[dt] = __builtin_amdgcn_mfma_f32_16x16x32_bf16(pf, vf, oacc[dt], 0, 0, 0);
        }
    }
    float lr4[4];
#pragma unroll
    for (int r = 0; r < 4; r++) lr4[r] = __shfl(l_run, (lane & 48) + lg * 4 + r, 64);
#pragma unroll
    for (int dt = 0; dt < 4; dt++)
#pragma unroll
        for (int r = 0; r < 4; r++) {
            float v = oacc[dt][r] / lr4[r];
            out[(size_t)(b * Nn + q0 + lg * 4 + r) * Dd + h * 64 + dt * 16 + lr] = f2bf(v);
        }
}

// ---------------- launch ----------------
extern "C" void kernel_launch(void* const* d_in, const int* in_sizes, int n_in,
                              void* d_out, int out_size, void* d_ws, size_t ws_size,
                              hipStream_t stream) {
    const float* x      = (const float*)d_in[0];
    const float* coords = (const float*)d_in[1];
    const float* w_qkv  = (const float*)d_in[2];
    const float* b_qkv  = (const float*)d_in[3];
    const float* w_out  = (const float*)d_in[4];
    const float* b_out  = (const float*)d_in[5];
    const float* w_ff1  = (const float*)d_in[6];
    const float* b_ff1  = (const float*)d_in[7];
    const float* w_ff2  = (const float*)d_in[8];
    const float* b_ff2  = (const float*)d_in[9];
    const float* g1     = (const float*)d_in[10];
    const float* beta1  = (const float*)d_in[11];
    const float* g2     = (const float*)d_in[12];
    const float* beta2  = (const float*)d_in[13];

    char* ws = (char*)d_ws;
    size_t off = 0;
    auto alloc = [&](size_t bytes) {
        char* p = ws + off;
        off += (bytes + 255) & ~(size_t)255;
        return p;
    };
    unsigned short* w_qkv_t = (unsigned short*)alloc((size_t)QKVN * Dd * 2);
    unsigned short* w_out_t = (unsigned short*)alloc((size_t)Dd * Dd * 2);
    unsigned short* w_ff1_t = (unsigned short*)alloc((size_t)FFf * Dd * 2);
    unsigned short* w_ff2_t = (unsigned short*)alloc((size_t)Dd * FFf * 2);
    float4*         c4      = (float4*)alloc((size_t)MTOK * 16);
    unsigned short* xn      = (unsigned short*)alloc((size_t)MTOK * Dd * 2);
    unsigned short* qkv     = (unsigned short*)alloc((size_t)MTOK * QKVN * 2);
    unsigned short* attn_o  = (unsigned short*)alloc((size_t)MTOK * Dd * 2);
    float*          x2      = (float*)alloc((size_t)MTOK * Dd * 4);
    unsigned short* hbuf    = (unsigned short*)alloc((size_t)MTOK * FFf * 2);

    dim3 tb(32, 8);
    k_transpose<<<dim3(QKVN / 32, Dd / 32), tb, 0, stream>>>(w_qkv, w_qkv_t, Dd, QKVN);
    k_transpose<<<dim3(Dd / 32, Dd / 32), tb, 0, stream>>>(w_out, w_out_t, Dd, Dd);
    k_transpose<<<dim3(FFf / 32, Dd / 32), tb, 0, stream>>>(w_ff1, w_ff1_t, Dd, FFf);
    k_transpose<<<dim3(Dd / 32, FFf / 32), tb, 0, stream>>>(w_ff2, w_ff2_t, FFf, Dd);
    k_coords<<<(MTOK + 255) / 256, 256, 0, stream>>>(coords, c4, MTOK);

    k_ln<<<MTOK, 256, 0, stream>>>(x, g1, beta1, xn);
    k_gemm<0><<<dim3(QKVN / 128, MTOK / 128), 256, 0, stream>>>(
        xn, w_qkv_t, b_qkv, nullptr, qkv, MTOK, QKVN, Dd);
    k_attn<<<dim3(Nn / 16, Hh, Bb), 64, 0, stream>>>(qkv, c4, attn_o);
    k_gemm<2><<<dim3(Dd / 128, MTOK / 128), 256, 0, stream>>>(
        attn_o, w_out_t, b_out, x, x2, MTOK, Dd, Dd);
    k_ln<<<MTOK, 256, 0, stream>>>(x2, g2, beta2, xn);
    k_gemm<1><<<dim3(FFf / 128, MTOK / 128), 256, 0, stream>>>(
        xn, w_ff1_t, b_ff1, nullptr, hbuf, MTOK, FFf, Dd);
    k_gemm<2><<<dim3(Dd / 128, MTOK / 128), 256, 0, stream>>>(
        hbuf, w_ff2_t, b_ff2, x2, (float*)d_out, MTOK, Dd, FFf);
}

// Round 2
// 310.229 us; speedup vs baseline: 1.2487x; 1.2487x over previous
//
#include <hip/hip_runtime.h>
#include <hip/hip_bf16.h>

typedef unsigned short ushort_t;
typedef __attribute__((ext_vector_type(4))) float f32x4;
typedef __attribute__((ext_vector_type(8))) short s16x8;

#define DEV static __device__ __forceinline__

constexpr int Bb = 2, Nn = 2048, Dd = 768, Hh = 12, FFf = 3072;
constexpr int MTOK = Bb * Nn;           // 4096
constexpr int QKVN = 3 * Dd;            // 2304

DEV unsigned short f2bf(float f) {
    union { float f; unsigned int i; } x; x.f = f;
    unsigned int r = x.i + 0x7FFFu + ((x.i >> 16) & 1u);
    return (unsigned short)(r >> 16);
}

DEV void gload16(const void* g, void* l) {
    __builtin_amdgcn_global_load_lds(
        (const __attribute__((address_space(1))) void*)g,
        (__attribute__((address_space(3))) void*)l, 16, 0, 0);
}

// ---------------- transpose + fp32->bf16 convert: in [K][N] -> out [N][K] ----------------
__global__ void k_transpose(const float* __restrict__ in, unsigned short* __restrict__ out,
                            int K, int N) {
    __shared__ float t[32][33];
    int bx = blockIdx.x * 32, by = blockIdx.y * 32;
    int tx = threadIdx.x, ty = threadIdx.y; // (32,8)
#pragma unroll
    for (int i = 0; i < 4; i++)
        t[ty + 8 * i][tx] = in[(size_t)(by + ty + 8 * i) * N + bx + tx];
    __syncthreads();
#pragma unroll
    for (int i = 0; i < 4; i++)
        out[(size_t)(bx + ty + 8 * i) * K + by + tx] = f2bf(t[tx][ty + 8 * i]);
}

// ---------------- pack coords (B,N,3) -> (B*N) float4 ----------------
__global__ void k_coords(const float* __restrict__ c, float4* __restrict__ out, int n) {
    int i = blockIdx.x * 256 + threadIdx.x;
    if (i < n) out[i] = make_float4(c[3 * i], c[3 * i + 1], c[3 * i + 2], 0.f);
}

// ---------------- LayerNorm fp32 -> bf16 ----------------
DEV float wred_sum(float v) {
#pragma unroll
    for (int o = 32; o; o >>= 1) v += __shfl_down(v, o, 64);
    return v;
}

__global__ __launch_bounds__(256) void k_ln(const float* __restrict__ x,
                                            const float* __restrict__ g,
                                            const float* __restrict__ be,
                                            unsigned short* __restrict__ out) {
    int row = blockIdx.x;
    const float* xr = x + (size_t)row * Dd;
    int t = threadIdx.x;
    float v0 = xr[t], v1 = xr[t + 256], v2 = xr[t + 512];
    float s = v0 + v1 + v2;
    float sq = v0 * v0 + v1 * v1 + v2 * v2;
    __shared__ float r1[4], r2[4];
    float ws = wred_sum(s), wq = wred_sum(sq);
    int wid = t >> 6, lane = t & 63;
    if (lane == 0) { r1[wid] = ws; r2[wid] = wq; }
    __syncthreads();
    s = r1[0] + r1[1] + r1[2] + r1[3];
    sq = r2[0] + r2[1] + r2[2] + r2[3];
    float mean = s * (1.f / Dd);
    float var = sq * (1.f / Dd) - mean * mean;
    float rs = rsqrtf(var + 1e-5f);
    unsigned short* orow = out + (size_t)row * Dd;
    orow[t]       = f2bf((v0 - mean) * rs * g[t]       + be[t]);
    orow[t + 256] = f2bf((v1 - mean) * rs * g[t + 256] + be[t + 256]);
    orow[t + 512] = f2bf((v2 - mean) * rs * g[t + 512] + be[t + 512]);
}

// ---------------- GEMM (m97 structure): A[M][K] bf16 @ Bt[N][K] bf16 + bias ----------------
// EPI 0: out bf16 = A@B + bias
// EPI 1: out bf16 = gelu(A@B + bias)
// EPI 2: out f32  = A@B + bias + res
template <int EPI>
__global__ __launch_bounds__(256) void k_gemm(const unsigned short* __restrict__ A,
                                              const unsigned short* __restrict__ Bt,
                                              const float* __restrict__ bias,
                                              const float* __restrict__ res,
                                              void* __restrict__ outp,
                                              int M, int N, int K) {
    constexpr int BM = 128, BN = 128, BK = 32;
    __shared__ unsigned short As[BM][BK];   // linear: global_load_lds writes base+lane*16
    __shared__ unsigned short Bs[BN][BK];
    int m0 = blockIdx.y * BM, n0 = blockIdx.x * BN;
    int t = threadIdx.x;
    int wid = t >> 6, lane = t & 63;
    int wr = wid >> 1, wc = wid & 1;
    int lg = lane >> 4, lr = lane & 15;
    f32x4 acc[4][4] = {};

    // staging addresses: wave wid covers rows [wid*32, wid*32+32), lane -> 16B chunk
    int srow = wid * 32 + (lane >> 2);
    int scol = (lane & 3) * 8;
    const unsigned short* Ag = A + (size_t)(m0 + srow) * K + scol;
    const unsigned short* Bg = Bt + (size_t)(n0 + srow) * K + scol;
    char* Al = (char*)&As[0][0] + wid * 2048;
    char* Bl = (char*)&Bs[0][0] + wid * 2048;

    for (int k0 = 0; k0 < K; k0 += BK) {
        __syncthreads();
        gload16(Ag + k0, Al);
        gload16(Ag + k0 + (size_t)16 * K, Al + 1024);
        gload16(Bg + k0, Bl);
        gload16(Bg + k0 + (size_t)16 * K, Bl + 1024);
        __syncthreads();   // compiler emits vmcnt(0) drain here -> LDS valid
        s16x8 af[4], bfr[4];
#pragma unroll
        for (int i = 0; i < 4; i++) {
            af[i]  = *(const s16x8*)&As[wr * 64 + i * 16 + lr][lg * 8];
            bfr[i] = *(const s16x8*)&Bs[wc * 64 + i * 16 + lr][lg * 8];
        }
#pragma unroll
        for (int mi = 0; mi < 4; mi++)
#pragma unroll
            for (int ni = 0; ni < 4; ni++)
                acc[mi][ni] = __builtin_amdgcn_mfma_f32_16x16x32_bf16(
                    af[mi], bfr[ni], acc[mi][ni], 0, 0, 0);
    }

    int mrow = m0 + wr * 64;
    int ncol = n0 + wc * 64;
#pragma unroll
    for (int mi = 0; mi < 4; mi++) {
#pragma unroll
        for (int ni = 0; ni < 4; ni++) {
            int nn = ncol + ni * 16 + lr;
            float bs = bias[nn];
#pragma unroll
            for (int r = 0; r < 4; r++) {
                int mm = mrow + mi * 16 + lg * 4 + r;
                float v = acc[mi][ni][r] + bs;
                if (EPI == 1) {
                    v = 0.5f * v * (1.f + erff(v * 0.70710678118f));
                    ((unsigned short*)outp)[(size_t)mm * N + nn] = f2bf(v);
                } else if (EPI == 2) {
                    v += res[(size_t)mm * N + nn];
                    ((float*)outp)[(size_t)mm * N + nn] = v;
                } else {
                    ((unsigned short*)outp)[(size_t)mm * N + nn] = f2bf(v);
                }
            }
        }
    }
}

// ---------------- fused masked flash attention, 4-wave blocks ----------------
// Block: 64 q-rows of one (b,h). Wave w: 16 q-rows. K/V tiles (64x64) staged in LDS.
constexpr int QBLK = 64, KBLK = 64;
__global__ __launch_bounds__(256) void k_attn(const unsigned short* __restrict__ qkv,
                                              const float4* __restrict__ c4,
                                              unsigned short* __restrict__ out) {
    // XCD-chunked swizzle: 768 blocks, 8 XCDs -> XCD x owns ids [x*96, (x+1)*96)
    int lin = blockIdx.x;
    int id = (lin & 7) * 96 + (lin >> 3);
    int qt = id & 31;
    int hb = id >> 5;            // 0..23
    int h = hb % Hh, b = hb / Hh;

    __shared__ unsigned short Ks[KBLK][72];   // [k][d], pad 8
    __shared__ unsigned short Vt[64][72];     // [d][k], pad 8
    __shared__ unsigned short Ps[4][16][72];  // per-wave P: [q][k], pad 8
    __shared__ float4 Cs[KBLK];

    int t = threadIdx.x, wid = t >> 6, lane = t & 63;
    int lg = lane >> 4, lr = lane & 15;

    const size_t rs = QKVN;
    const unsigned short* Qb = qkv + (size_t)b * Nn * rs + h * 64;
    const unsigned short* Kb = Qb + Dd;
    const unsigned short* Vb = Qb + 2 * Dd;
    int qbase = qt * QBLK + wid * 16;

    s16x8 qf0 = *(const s16x8*)(Qb + (size_t)(qbase + lr) * rs + lg * 8);
    s16x8 qf1 = *(const s16x8*)(Qb + (size_t)(qbase + lr) * rs + 32 + lg * 8);
    float4 cq = c4[b * Nn + qbase + lr];

    float m_run = -1e30f, l_run = 0.f;
    f32x4 oacc[4] = {};

    // staging map (V): thread covers k-pair (t&31)*2, d-chunk (t>>5)*8
    int vdch = (t >> 5) * 8, vkp = (t & 31) * 2;

    for (int k0 = 0; k0 < Nn; k0 += KBLK) {
        __syncthreads();
        // K tile: [64][64], vectorized rows
#pragma unroll
        for (int i = 0; i < 2; i++) {
            int item = t + 256 * i;
            int row = item >> 3, ch = (item & 7) * 8;
            *(s16x8*)&Ks[row][ch] = *(const s16x8*)(Kb + (size_t)(k0 + row) * rs + ch);
        }
        // V tile transposed: packed pair writes (b32), 2-way conflict free
        {
            s16x8 v0 = *(const s16x8*)(Vb + (size_t)(k0 + vkp) * rs + vdch);
            s16x8 v1 = *(const s16x8*)(Vb + (size_t)(k0 + vkp + 1) * rs + vdch);
#pragma unroll
            for (int j = 0; j < 8; j++) {
                unsigned int pack = (unsigned int)(unsigned short)v0[j] |
                                    ((unsigned int)(unsigned short)v1[j] << 16);
                *(unsigned int*)((char*)&Vt[0][0] + (size_t)(vdch + j) * 144 + vkp * 2) = pack;
            }
        }
        if (t < KBLK) Cs[t] = c4[b * Nn + k0 + t];
        __syncthreads();

        // QK^T (swapped): st[s] holds S^T for k-sub s: q=lr, k=s*16+lg*4+r
        f32x4 st[4];
#pragma unroll
        for (int s = 0; s < 4; s++) {
            s16x8 kf0 = *(const s16x8*)&Ks[s * 16 + lr][lg * 8];
            s16x8 kf1 = *(const s16x8*)&Ks[s * 16 + lr][32 + lg * 8];
            f32x4 z = {};
            z = __builtin_amdgcn_mfma_f32_16x16x32_bf16(kf0, qf0, z, 0, 0, 0);
            st[s] = __builtin_amdgcn_mfma_f32_16x16x32_bf16(kf1, qf1, z, 0, 0, 0);
        }
        // mask + scale
        float p[4][4];
        float mt = -1e30f;
#pragma unroll
        for (int s = 0; s < 4; s++) {
#pragma unroll
            for (int r = 0; r < 4; r++) {
                int kk = s * 16 + lg * 4 + r;
                float4 ck = Cs[kk];
                float dx = cq.x - ck.x, dy = cq.y - ck.y, dz = cq.z - ck.z;
                float d2 = dx * dx + dy * dy + dz * dz;
                float sv = st[s][r] * 0.125f;
                p[s][r] = (d2 <= 4.0f) ? sv : -1e30f;
                mt = fmaxf(mt, p[s][r]);
            }
        }
        mt = fmaxf(mt, __shfl_xor(mt, 16, 64));
        mt = fmaxf(mt, __shfl_xor(mt, 32, 64));
        float mn = fmaxf(m_run, mt);
        float fac = expf(m_run - mn);
        float lt = 0.f;
#pragma unroll
        for (int s = 0; s < 4; s++)
#pragma unroll
            for (int r = 0; r < 4; r++) {
                p[s][r] = (p[s][r] > -1e29f) ? expf(p[s][r] - mn) : 0.f;
                lt += p[s][r];
            }
        lt += __shfl_xor(lt, 16, 64);
        lt += __shfl_xor(lt, 32, 64);
        l_run = l_run * fac + lt;
        m_run = mn;
        // rescale O (rows q = lg*4+r)
        float fr[4];
#pragma unroll
        for (int r = 0; r < 4; r++) fr[r] = __shfl(fac, (lane & 48) + lg * 4 + r, 64);
#pragma unroll
        for (int dt = 0; dt < 4; dt++)
#pragma unroll
            for (int r = 0; r < 4; r++) oacc[dt][r] *= fr[r];
        // P -> per-wave LDS (re-fragment), then PV from LDS
#pragma unroll
        for (int s = 0; s < 4; s++)
#pragma unroll
            for (int r = 0; r < 4; r++)
                Ps[wid][lr][s * 16 + lg * 4 + r] = f2bf(p[s][r]);
#pragma unroll
        for (int c = 0; c < 2; c++) {
            s16x8 pf = *(const s16x8*)&Ps[wid][lr][c * 32 + lg * 8];
#pragma unroll
            for (int dt = 0; dt < 4; dt++) {
                s16x8 vf = *(const s16x8*)&Vt[dt * 16 + lr][c * 32 + lg * 8];
                oacc[dt] = __builtin_amdgcn_mfma_f32_16x16x32_bf16(pf, vf, oacc[dt], 0, 0, 0);
            }
        }
    }
    float lr4[4];
#pragma unroll
    for (int r = 0; r < 4; r++) lr4[r] = __shfl(l_run, (lane & 48) + lg * 4 + r, 64);
#pragma unroll
    for (int dt = 0; dt < 4; dt++)
#pragma unroll
        for (int r = 0; r < 4; r++) {
            float v = oacc[dt][r] / lr4[r];
            out[(size_t)(b * Nn + qbase + lg * 4 + r) * Dd + h * 64 + dt * 16 + lr] = f2bf(v);
        }
}

// ---------------- launch ----------------
extern "C" void kernel_launch(void* const* d_in, const int* in_sizes, int n_in,
                              void* d_out, int out_size, void* d_ws, size_t ws_size,
                              hipStream_t stream) {
    const float* x      = (const float*)d_in[0];
    const float* coords = (const float*)d_in[1];
    const float* w_qkv  = (const float*)d_in[2];
    const float* b_qkv  = (const float*)d_in[3];
    const float* w_out  = (const float*)d_in[4];
    const float* b_out  = (const float*)d_in[5];
    const float* w_ff1  = (const float*)d_in[6];
    const float* b_ff1  = (const float*)d_in[7];
    const float* w_ff2  = (const float*)d_in[8];
    const float* b_ff2  = (const float*)d_in[9];
    const float* g1     = (const float*)d_in[10];
    const float* beta1  = (const float*)d_in[11];
    const float* g2     = (const float*)d_in[12];
    const float* beta2  = (const float*)d_in[13];

    char* ws = (char*)d_ws;
    size_t off = 0;
    auto alloc = [&](size_t bytes) {
        char* p = ws + off;
        off += (bytes + 255) & ~(size_t)255;
        return p;
    };
    unsigned short* w_qkv_t = (unsigned short*)alloc((size_t)QKVN * Dd * 2);
    unsigned short* w_out_t = (unsigned short*)alloc((size_t)Dd * Dd * 2);
    unsigned short* w_ff1_t = (unsigned short*)alloc((size_t)FFf * Dd * 2);
    unsigned short* w_ff2_t = (unsigned short*)alloc((size_t)Dd * FFf * 2);
    float4*         c4      = (float4*)alloc((size_t)MTOK * 16);
    unsigned short* xn      = (unsigned short*)alloc((size_t)MTOK * Dd * 2);
    unsigned short* qkv     = (unsigned short*)alloc((size_t)MTOK * QKVN * 2);
    unsigned short* attn_o  = (unsigned short*)alloc((size_t)MTOK * Dd * 2);
    float*          x2      = (float*)alloc((size_t)MTOK * Dd * 4);
    unsigned short* hbuf    = (unsigned short*)alloc((size_t)MTOK * FFf * 2);

    dim3 tb(32, 8);
    k_transpose<<<dim3(QKVN / 32, Dd / 32), tb, 0, stream>>>(w_qkv, w_qkv_t, Dd, QKVN);
    k_transpose<<<dim3(Dd / 32, Dd / 32), tb, 0, stream>>>(w_out, w_out_t, Dd, Dd);
    k_transpose<<<dim3(FFf / 32, Dd / 32), tb, 0, stream>>>(w_ff1, w_ff1_t, Dd, FFf);
    k_transpose<<<dim3(Dd / 32, FFf / 32), tb, 0, stream>>>(w_ff2, w_ff2_t, FFf, Dd);
    k_coords<<<(MTOK + 255) / 256, 256, 0, stream>>>(coords, c4, MTOK);

    k_ln<<<MTOK, 256, 0, stream>>>(x, g1, beta1, xn);
    k_gemm<0><<<dim3(QKVN / 128, MTOK / 128), 256, 0, stream>>>(
        xn, w_qkv_t, b_qkv, nullptr, qkv, MTOK, QKVN, Dd);
    k_attn<<<dim3((Nn / QBLK) * Hh * Bb), 256, 0, stream>>>(qkv, c4, attn_o);
    k_gemm<2><<<dim3(Dd / 128, MTOK / 128), 256, 0, stream>>>(
        attn_o, w_out_t, b_out, x, x2, MTOK, Dd, Dd);
    k_ln<<<MTOK, 256, 0, stream>>>(x2, g2, beta2, xn);
    k_gemm<1><<<dim3(FFf / 128, MTOK / 128), 256, 0, stream>>>(
        xn, w_ff1_t, b_ff1, nullptr, hbuf, MTOK, FFf, Dd);
    k_gemm<2><<<dim3(Dd / 128, MTOK / 128), 256, 0, stream>>>(
        hbuf, w_ff2_t, b_ff2, x2, (float*)d_out, MTOK, Dd, FFf);
}

// Round 3
// 276.546 us; speedup vs baseline: 1.4008x; 1.1218x over previous
//
#include <hip/hip_runtime.h>
#include <hip/hip_bf16.h>

typedef unsigned short ushort_t;
typedef __attribute__((ext_vector_type(4))) float f32x4;
typedef __attribute__((ext_vector_type(8))) short s16x8;

#define DEV static __device__ __forceinline__

constexpr int Bb = 2, Nn = 2048, Dd = 768, Hh = 12, FFf = 3072;
constexpr int MTOK = Bb * Nn;           // 4096
constexpr int QKVN = 3 * Dd;            // 2304

DEV unsigned short f2bf(float f) {
    union { float f; unsigned int i; } x; x.f = f;
    unsigned int r = x.i + 0x7FFFu + ((x.i >> 16) & 1u);
    return (unsigned short)(r >> 16);
}

DEV void gload16(const void* g, void* l) {
    __builtin_amdgcn_global_load_lds(
        (const __attribute__((address_space(1))) void*)g,
        (__attribute__((address_space(3))) void*)l, 16, 0, 0);
}

// ---------------- transpose + fp32->bf16 convert: in [K][N] -> out [N][K] ----------------
__global__ void k_transpose(const float* __restrict__ in, unsigned short* __restrict__ out,
                            int K, int N) {
    __shared__ float t[32][33];
    int bx = blockIdx.x * 32, by = blockIdx.y * 32;
    int tx = threadIdx.x, ty = threadIdx.y; // (32,8)
#pragma unroll
    for (int i = 0; i < 4; i++)
        t[ty + 8 * i][tx] = in[(size_t)(by + ty + 8 * i) * N + bx + tx];
    __syncthreads();
#pragma unroll
    for (int i = 0; i < 4; i++)
        out[(size_t)(bx + ty + 8 * i) * K + by + tx] = f2bf(t[tx][ty + 8 * i]);
}

// ---------------- pack coords (B,N,3) -> (B*N) float4 ----------------
__global__ void k_coords(const float* __restrict__ c, float4* __restrict__ out, int n) {
    int i = blockIdx.x * 256 + threadIdx.x;
    if (i < n) out[i] = make_float4(c[3 * i], c[3 * i + 1], c[3 * i + 2], 0.f);
}

// ---------------- radius mask bits: mb[b][q][w] bit j = (d2(q, w*64+j) <= 4) ----------------
__global__ __launch_bounds__(256) void k_mask(const float4* __restrict__ c4,
                                              unsigned long long* __restrict__ mb) {
    int qt = blockIdx.x, ks = blockIdx.y, b = blockIdx.z;  // (32, 8, B)
    __shared__ float4 ck[256];
    int t = threadIdx.x;
    ck[t] = c4[b * Nn + ks * 256 + t];
    __syncthreads();
    int r = t >> 2, c = t & 3;
    int q = qt * 64 + r;
    float4 cq = c4[b * Nn + q];
    unsigned long long w = 0;
#pragma unroll 8
    for (int j = 0; j < 64; j++) {
        float4 k4 = ck[c * 64 + j];
        float dx = __fsub_rn(cq.x, k4.x);
        float dy = __fsub_rn(cq.y, k4.y);
        float dz = __fsub_rn(cq.z, k4.z);
        float d2 = __fadd_rn(__fadd_rn(__fmul_rn(dx, dx), __fmul_rn(dy, dy)),
                             __fmul_rn(dz, dz));
        if (d2 <= 4.0f) w |= 1ull << j;
    }
    mb[((size_t)(b * Nn + q) << 5) + ks * 4 + c] = w;
}

// ---------------- LayerNorm fp32 -> bf16 ----------------
DEV float wred_sum(float v) {
#pragma unroll
    for (int o = 32; o; o >>= 1) v += __shfl_down(v, o, 64);
    return v;
}

__global__ __launch_bounds__(256) void k_ln(const float* __restrict__ x,
                                            const float* __restrict__ g,
                                            const float* __restrict__ be,
                                            unsigned short* __restrict__ out) {
    int row = blockIdx.x;
    const float* xr = x + (size_t)row * Dd;
    int t = threadIdx.x;
    float v0 = xr[t], v1 = xr[t + 256], v2 = xr[t + 512];
    float s = v0 + v1 + v2;
    float sq = v0 * v0 + v1 * v1 + v2 * v2;
    __shared__ float r1[4], r2[4];
    float ws = wred_sum(s), wq = wred_sum(sq);
    int wid = t >> 6, lane = t & 63;
    if (lane == 0) { r1[wid] = ws; r2[wid] = wq; }
    __syncthreads();
    s = r1[0] + r1[1] + r1[2] + r1[3];
    sq = r2[0] + r2[1] + r2[2] + r2[3];
    float mean = s * (1.f / Dd);
    float var = sq * (1.f / Dd) - mean * mean;
    float rs = rsqrtf(var + 1e-5f);
    unsigned short* orow = out + (size_t)row * Dd;
    orow[t]       = f2bf((v0 - mean) * rs * g[t]       + be[t]);
    orow[t + 256] = f2bf((v1 - mean) * rs * g[t + 256] + be[t + 256]);
    orow[t + 512] = f2bf((v2 - mean) * rs * g[t + 512] + be[t + 512]);
}

// ---------------- GEMM (m97 structure): A[M][K] bf16 @ Bt[N][K] bf16 + bias ----------------
template <int EPI>
__global__ __launch_bounds__(256) void k_gemm(const unsigned short* __restrict__ A,
                                              const unsigned short* __restrict__ Bt,
                                              const float* __restrict__ bias,
                                              const float* __restrict__ res,
                                              void* __restrict__ outp,
                                              int M, int N, int K) {
    constexpr int BM = 128, BN = 128, BK = 32;
    __shared__ unsigned short As[BM][BK];
    __shared__ unsigned short Bs[BN][BK];
    int m0 = blockIdx.y * BM, n0 = blockIdx.x * BN;
    int t = threadIdx.x;
    int wid = t >> 6, lane = t & 63;
    int wr = wid >> 1, wc = wid & 1;
    int lg = lane >> 4, lr = lane & 15;
    f32x4 acc[4][4] = {};

    int srow = wid * 32 + (lane >> 2);
    int scol = (lane & 3) * 8;
    const unsigned short* Ag = A + (size_t)(m0 + srow) * K + scol;
    const unsigned short* Bg = Bt + (size_t)(n0 + srow) * K + scol;
    char* Al = (char*)&As[0][0] + wid * 2048;
    char* Bl = (char*)&Bs[0][0] + wid * 2048;

    for (int k0 = 0; k0 < K; k0 += BK) {
        __syncthreads();
        gload16(Ag + k0, Al);
        gload16(Ag + k0 + (size_t)16 * K, Al + 1024);
        gload16(Bg + k0, Bl);
        gload16(Bg + k0 + (size_t)16 * K, Bl + 1024);
        __syncthreads();
        s16x8 af[4], bfr[4];
#pragma unroll
        for (int i = 0; i < 4; i++) {
            af[i]  = *(const s16x8*)&As[wr * 64 + i * 16 + lr][lg * 8];
            bfr[i] = *(const s16x8*)&Bs[wc * 64 + i * 16 + lr][lg * 8];
        }
#pragma unroll
        for (int mi = 0; mi < 4; mi++)
#pragma unroll
            for (int ni = 0; ni < 4; ni++)
                acc[mi][ni] = __builtin_amdgcn_mfma_f32_16x16x32_bf16(
                    af[mi], bfr[ni], acc[mi][ni], 0, 0, 0);
    }

    int mrow = m0 + wr * 64;
    int ncol = n0 + wc * 64;
#pragma unroll
    for (int mi = 0; mi < 4; mi++) {
#pragma unroll
        for (int ni = 0; ni < 4; ni++) {
            int nn = ncol + ni * 16 + lr;
            float bs = bias[nn];
#pragma unroll
            for (int r = 0; r < 4; r++) {
                int mm = mrow + mi * 16 + lg * 4 + r;
                float v = acc[mi][ni][r] + bs;
                if (EPI == 1) {
                    v = 0.5f * v * (1.f + erff(v * 0.70710678118f));
                    ((unsigned short*)outp)[(size_t)mm * N + nn] = f2bf(v);
                } else if (EPI == 2) {
                    v += res[(size_t)mm * N + nn];
                    ((float*)outp)[(size_t)mm * N + nn] = v;
                } else {
                    ((unsigned short*)outp)[(size_t)mm * N + nn] = f2bf(v);
                }
            }
        }
    }
}

// ---------------- fused masked flash attention, 4-wave blocks, swizzled LDS ----------------
constexpr int QBLK = 64, KBLK = 64;
constexpr float SC2 = 0.125f * 1.44269504088896340736f;  // score scale in log2 domain
constexpr float PMASK = -3.0e38f;                        // masked sentinel (< m-init)
constexpr float MINIT = -1.0e30f;

__global__ __launch_bounds__(256) void k_attn(const unsigned short* __restrict__ qkv,
                                              const uint2* __restrict__ mb,
                                              unsigned short* __restrict__ out) {
    int lin = blockIdx.x;
    int id = (lin & 7) * 96 + (lin >> 3);   // XCD-chunked swizzle (768 = 8*96)
    int qt = id & 31;
    int hb = id >> 5;
    int h = hb % Hh, b = hb / Hh;

    __shared__ unsigned short Ks[64 * 64];   // linear [64][64], 16B-chunk XOR swizzled
    __shared__ unsigned short Vt[64 * 64];   // transposed V, same swizzle
    __shared__ unsigned short Ps[4][16 * 64];

    int t = threadIdx.x, wid = t >> 6, lane = t & 63;
    int lg = lane >> 4, lr = lane & 15;
    int sw = lr & 7;

    const size_t rs = QKVN;
    const unsigned short* Qb = qkv + (size_t)b * Nn * rs + h * 64;
    const unsigned short* Kb = Qb + Dd;
    const unsigned short* Vb = Qb + 2 * Dd;
    int qbase = qt * QBLK + wid * 16;

    s16x8 qf0 = *(const s16x8*)(Qb + (size_t)(qbase + lr) * rs + lg * 8);
    s16x8 qf1 = *(const s16x8*)(Qb + (size_t)(qbase + lr) * rs + 32 + lg * 8);

    // K staging: pre-swizzled per-lane global source, linear LDS dest (m173)
    int krow = wid * 8 + (lane >> 3);
    int kch = (lane & 7) ^ ((lane >> 3) & 7);
    const unsigned short* Kg = Kb + (size_t)krow * rs + kch * 8;
    char* Kl = (char*)Ks + wid * 1024;

    // V staging: thread covers k-pair (t&31)*2, d-chunk (t>>5)*8
    int vd = (t >> 5) * 8, vkp = (t & 31) * 2;
    const unsigned short* Vg = Vb + (size_t)vkp * rs + vd;

    const uint2* mrow = mb + ((size_t)(b * Nn + qbase + lr) << 5);

    float m2 = MINIT, l_run = 0.f;
    f32x4 oacc[4] = {};

    for (int k0 = 0; k0 < Nn; k0 += KBLK) {
        __syncthreads();
        gload16(Kg + (size_t)k0 * rs, Kl);
        gload16(Kg + (size_t)(k0 + 32) * rs, Kl + 4096);
        s16x8 v0 = *(const s16x8*)(Vg + (size_t)k0 * rs);
        s16x8 v1 = *(const s16x8*)(Vg + (size_t)(k0 + 1) * rs);
        uint2 Mw = mrow[k0 >> 6];
#pragma unroll
        for (int j = 0; j < 8; j++) {
            int d = vd + j;
            unsigned int pack = (unsigned int)(unsigned short)v0[j] |
                                ((unsigned int)(unsigned short)v1[j] << 16);
            int byte = d * 128 + ((((vkp >> 3) ^ (d & 7)) << 4)) + (vkp & 7) * 2;
            *(unsigned int*)((char*)Vt + byte) = pack;
        }
        __syncthreads();

        __builtin_amdgcn_s_setprio(1);
        f32x4 st[4];
#pragma unroll
        for (int s = 0; s < 4; s++) {
            const char* kr = (const char*)Ks + (s * 16 + lr) * 128;
            s16x8 kf0 = *(const s16x8*)(kr + ((lg ^ sw) << 4));
            s16x8 kf1 = *(const s16x8*)(kr + (((4 + lg) ^ sw) << 4));
            f32x4 z = {};
            z = __builtin_amdgcn_mfma_f32_16x16x32_bf16(kf0, qf0, z, 0, 0, 0);
            st[s] = __builtin_amdgcn_mfma_f32_16x16x32_bf16(kf1, qf1, z, 0, 0, 0);
        }
        __builtin_amdgcn_s_setprio(0);

        // mask + scale (log2 domain), tile max
        float p[4][4];
        float mt = PMASK;
#pragma unroll
        for (int s = 0; s < 4; s++) {
            unsigned int wsel = (s < 2) ? Mw.x : Mw.y;
#pragma unroll
            for (int r = 0; r < 4; r++) {
                float sv = st[s][r] * SC2;
                unsigned int bit = (wsel >> ((s & 1) * 16 + lg * 4 + r)) & 1u;
                p[s][r] = bit ? sv : PMASK;
                mt = fmaxf(mt, p[s][r]);
            }
        }
        mt = fmaxf(mt, __shfl_xor(mt, 16, 64));
        mt = fmaxf(mt, __shfl_xor(mt, 32, 64));

        // defer-max (T13): rescale only when some row's max grows past slack
        if (!__all(mt <= m2 + 11.5416f)) {
            float mn2 = fmaxf(m2, mt);
            float fac = __builtin_amdgcn_exp2f(m2 - mn2);
            l_run *= fac;
            m2 = mn2;
            float fr[4];
#pragma unroll
            for (int r = 0; r < 4; r++) fr[r] = __shfl(fac, (lane & 48) + lg * 4 + r, 64);
#pragma unroll
            for (int dt = 0; dt < 4; dt++)
#pragma unroll
                for (int r = 0; r < 4; r++) oacc[dt][r] *= fr[r];
        }

        float lt = 0.f;
#pragma unroll
        for (int s = 0; s < 4; s++)
#pragma unroll
            for (int r = 0; r < 4; r++) {
                p[s][r] = __builtin_amdgcn_exp2f(p[s][r] - m2);  // masked: -3e38-m2 -> 0
                lt += p[s][r];
            }
        lt += __shfl_xor(lt, 16, 64);
        lt += __shfl_xor(lt, 32, 64);
        l_run += lt;

        // P -> per-wave LDS, packed u64 writes, swizzled
        char* pw = (char*)&Ps[wid][0] + lr * 128;
#pragma unroll
        for (int s = 0; s < 4; s++) {
            unsigned int lo = (unsigned int)f2bf(p[s][0]) | ((unsigned int)f2bf(p[s][1]) << 16);
            unsigned int hi = (unsigned int)f2bf(p[s][2]) | ((unsigned int)f2bf(p[s][3]) << 16);
            unsigned long long u = (unsigned long long)lo | ((unsigned long long)hi << 32);
            int chunk = (s * 2 + (lg >> 1)) ^ sw;
            *(unsigned long long*)(pw + (chunk << 4) + (lg & 1) * 8) = u;
        }

        __builtin_amdgcn_s_setprio(1);
#pragma unroll
        for (int c = 0; c < 2; c++) {
            s16x8 pf = *(const s16x8*)(pw + (((c * 4 + lg) ^ sw) << 4));
#pragma unroll
            for (int dt = 0; dt < 4; dt++) {
                const char* vr = (const char*)Vt + (dt * 16 + lr) * 128;
                s16x8 vf = *(const s16x8*)(vr + (((c * 4 + lg) ^ sw) << 4));
                oacc[dt] = __builtin_amdgcn_mfma_f32_16x16x32_bf16(pf, vf, oacc[dt], 0, 0, 0);
            }
        }
        __builtin_amdgcn_s_setprio(0);
    }
    float lr4[4];
#pragma unroll
    for (int r = 0; r < 4; r++) lr4[r] = __shfl(l_run, (lane & 48) + lg * 4 + r, 64);
#pragma unroll
    for (int dt = 0; dt < 4; dt++)
#pragma unroll
        for (int r = 0; r < 4; r++) {
            float v = oacc[dt][r] / lr4[r];
            out[(size_t)(b * Nn + qbase + lg * 4 + r) * Dd + h * 64 + dt * 16 + lr] = f2bf(v);
        }
}

// ---------------- launch ----------------
extern "C" void kernel_launch(void* const* d_in, const int* in_sizes, int n_in,
                              void* d_out, int out_size, void* d_ws, size_t ws_size,
                              hipStream_t stream) {
    const float* x      = (const float*)d_in[0];
    const float* coords = (const float*)d_in[1];
    const float* w_qkv  = (const float*)d_in[2];
    const float* b_qkv  = (const float*)d_in[3];
    const float* w_out  = (const float*)d_in[4];
    const float* b_out  = (const float*)d_in[5];
    const float* w_ff1  = (const float*)d_in[6];
    const float* b_ff1  = (const float*)d_in[7];
    const float* w_ff2  = (const float*)d_in[8];
    const float* b_ff2  = (const float*)d_in[9];
    const float* g1     = (const float*)d_in[10];
    const float* beta1  = (const float*)d_in[11];
    const float* g2     = (const float*)d_in[12];
    const float* beta2  = (const float*)d_in[13];

    char* ws = (char*)d_ws;
    size_t off = 0;
    auto alloc = [&](size_t bytes) {
        char* p = ws + off;
        off += (bytes + 255) & ~(size_t)255;
        return p;
    };
    unsigned short* w_qkv_t = (unsigned short*)alloc((size_t)QKVN * Dd * 2);
    unsigned short* w_out_t = (unsigned short*)alloc((size_t)Dd * Dd * 2);
    unsigned short* w_ff1_t = (unsigned short*)alloc((size_t)FFf * Dd * 2);
    unsigned short* w_ff2_t = (unsigned short*)alloc((size_t)Dd * FFf * 2);
    float4*         c4      = (float4*)alloc((size_t)MTOK * 16);
    unsigned long long* mbits = (unsigned long long*)alloc((size_t)MTOK * 32 * 8);
    unsigned short* xn      = (unsigned short*)alloc((size_t)MTOK * Dd * 2);
    unsigned short* qkv     = (unsigned short*)alloc((size_t)MTOK * QKVN * 2);
    unsigned short* attn_o  = (unsigned short*)alloc((size_t)MTOK * Dd * 2);
    float*          x2      = (float*)alloc((size_t)MTOK * Dd * 4);
    unsigned short* hbuf    = (unsigned short*)alloc((size_t)MTOK * FFf * 2);

    dim3 tb(32, 8);
    k_transpose<<<dim3(QKVN / 32, Dd / 32), tb, 0, stream>>>(w_qkv, w_qkv_t, Dd, QKVN);
    k_transpose<<<dim3(Dd / 32, Dd / 32), tb, 0, stream>>>(w_out, w_out_t, Dd, Dd);
    k_transpose<<<dim3(FFf / 32, Dd / 32), tb, 0, stream>>>(w_ff1, w_ff1_t, Dd, FFf);
    k_transpose<<<dim3(Dd / 32, FFf / 32), tb, 0, stream>>>(w_ff2, w_ff2_t, FFf, Dd);
    k_coords<<<(MTOK + 255) / 256, 256, 0, stream>>>(coords, c4, MTOK);
    k_mask<<<dim3(Nn / 64, 8, Bb), 256, 0, stream>>>(c4, mbits);

    k_ln<<<MTOK, 256, 0, stream>>>(x, g1, beta1, xn);
    k_gemm<0><<<dim3(QKVN / 128, MTOK / 128), 256, 0, stream>>>(
        xn, w_qkv_t, b_qkv, nullptr, qkv, MTOK, QKVN, Dd);
    k_attn<<<dim3((Nn / QBLK) * Hh * Bb), 256, 0, stream>>>(qkv, (const uint2*)mbits, attn_o);
    k_gemm<2><<<dim3(Dd / 128, MTOK / 128), 256, 0, stream>>>(
        attn_o, w_out_t, b_out, x, x2, MTOK, Dd, Dd);
    k_ln<<<MTOK, 256, 0, stream>>>(x2, g2, beta2, xn);
    k_gemm<1><<<dim3(FFf / 128, MTOK / 128), 256, 0, stream>>>(
        xn, w_ff1_t, b_ff1, nullptr, hbuf, MTOK, FFf, Dd);
    k_gemm<2><<<dim3(Dd / 128, MTOK / 128), 256, 0, stream>>>(
        hbuf, w_ff2_t, b_ff2, x2, (float*)d_out, MTOK, Dd, FFf);
}